// Round 1
// baseline (165.759 us; speedup 1.0000x reference)
//
#include <hip/hip_runtime.h>

#define KN 1000000
#define NCOLS 70400
#define SENTINEL -9999999.0f

// Order-preserving float<->uint encoding for atomicMax on floats.
__device__ __forceinline__ unsigned encodeF(float f) {
    unsigned b = __float_as_uint(f);
    return (b & 0x80000000u) ? ~b : (b | 0x80000000u);
}
__device__ __forceinline__ float decodeF(unsigned e) {
    unsigned b = (e & 0x80000000u) ? (e & 0x7fffffffu) : ~e;
    return __uint_as_float(b);
}

__global__ __launch_bounds__(256) void init_kernel(unsigned* __restrict__ outU) {
    int gid = blockIdx.x * blockDim.x + threadIdx.x;
    if (gid < NCOLS) outU[gid] = encodeF(SENTINEL);
}

__global__ __launch_bounds__(256) void mlp_scatter_kernel(
    const float* __restrict__ x,      // (4, K) : input_1[0,:,0,:]
    const int*   __restrict__ tidx,   // (K, 2) int32 pairs (row, col)
    const float* __restrict__ W1, const float* __restrict__ b1,   // (18,4)
    const float* __restrict__ W2, const float* __restrict__ b2,   // (36,18)
    const float* __restrict__ W3, const float* __restrict__ b3,   // (36,36)
    const float* __restrict__ W4, const float* __restrict__ b4,   // (1,36)
    unsigned* __restrict__ outU)
{
    // LDS-staged weights. W2/W3 stored COLUMN-major so the j-loop reads
    // contiguous float4 (ds_read_b128 broadcast, 1 read per 4 FMAs per elem).
    __shared__ __align__(16) float sW1[72];        // row-major (18x4), rows are float4
    __shared__ float sb1[18];
    __shared__ __align__(16) float sW2t[18 * 36];  // sW2t[i*36+j] = W2[j*18+i]
    __shared__ float sb2[36];
    __shared__ __align__(16) float sW3t[36 * 36];  // sW3t[i*36+j] = W3[j*36+i]
    __shared__ float sb3[36];
    __shared__ __align__(16) float sW4[36];
    __shared__ float sb4;

    const int t = threadIdx.x;
    for (int i = t; i < 72; i += 256) sW1[i] = W1[i];
    for (int i = t; i < 18; i += 256) sb1[i] = b1[i];
    for (int i = t; i < 648; i += 256) { int ii = i / 36, j = i % 36; sW2t[i] = W2[j * 18 + ii]; }
    for (int i = t; i < 36; i += 256) sb2[i] = b2[i];
    for (int i = t; i < 1296; i += 256) { int ii = i / 36, j = i % 36; sW3t[i] = W3[j * 36 + ii]; }
    for (int i = t; i < 36; i += 256) sb3[i] = b3[i];
    for (int i = t; i < 36; i += 256) sW4[i] = W4[i];
    if (t == 0) sb4 = b4[0];
    __syncthreads();

    const int gid = blockIdx.x * blockDim.x + t;
    const int k0 = gid * 2;              // each thread handles elements k0, k0+1
    if (k0 >= KN) return;

    // Load the 4 input channels for both elements (coalesced float2).
    float2 xv[4];
#pragma unroll
    for (int c = 0; c < 4; ++c) xv[c] = *(const float2*)(x + c * KN + k0);

    // ---- layer 1: (18,4) ----
    float h1a[18], h1b[18];
#pragma unroll
    for (int j = 0; j < 18; ++j) {
        float4 w = *(const float4*)(&sW1[4 * j]);
        float bj = sb1[j];
        float a0 = fmaf(w.x, xv[0].x, fmaf(w.y, xv[1].x, fmaf(w.z, xv[2].x, fmaf(w.w, xv[3].x, bj))));
        float a1 = fmaf(w.x, xv[0].y, fmaf(w.y, xv[1].y, fmaf(w.z, xv[2].y, fmaf(w.w, xv[3].y, bj))));
        h1a[j] = fmaxf(a0, 0.0f);
        h1b[j] = fmaxf(a1, 0.0f);
    }

    // ---- layer 2: (36,18) ----
    float h2a[36], h2b[36];
#pragma unroll
    for (int j = 0; j < 36; ++j) { float bj = sb2[j]; h2a[j] = bj; h2b[j] = bj; }
#pragma unroll
    for (int i = 0; i < 18; ++i) {
        float a0 = h1a[i], a1 = h1b[i];
#pragma unroll
        for (int q = 0; q < 9; ++q) {
            float4 w = *(const float4*)(&sW2t[i * 36 + q * 4]);
            h2a[4 * q + 0] = fmaf(w.x, a0, h2a[4 * q + 0]);
            h2a[4 * q + 1] = fmaf(w.y, a0, h2a[4 * q + 1]);
            h2a[4 * q + 2] = fmaf(w.z, a0, h2a[4 * q + 2]);
            h2a[4 * q + 3] = fmaf(w.w, a0, h2a[4 * q + 3]);
            h2b[4 * q + 0] = fmaf(w.x, a1, h2b[4 * q + 0]);
            h2b[4 * q + 1] = fmaf(w.y, a1, h2b[4 * q + 1]);
            h2b[4 * q + 2] = fmaf(w.z, a1, h2b[4 * q + 2]);
            h2b[4 * q + 3] = fmaf(w.w, a1, h2b[4 * q + 3]);
        }
    }
#pragma unroll
    for (int j = 0; j < 36; ++j) { h2a[j] = fmaxf(h2a[j], 0.0f); h2b[j] = fmaxf(h2b[j], 0.0f); }

    // ---- layer 3: (36,36) ----
    float h3a[36], h3b[36];
#pragma unroll
    for (int j = 0; j < 36; ++j) { float bj = sb3[j]; h3a[j] = bj; h3b[j] = bj; }
#pragma unroll
    for (int i = 0; i < 36; ++i) {
        float a0 = h2a[i], a1 = h2b[i];
#pragma unroll
        for (int q = 0; q < 9; ++q) {
            float4 w = *(const float4*)(&sW3t[i * 36 + q * 4]);
            h3a[4 * q + 0] = fmaf(w.x, a0, h3a[4 * q + 0]);
            h3a[4 * q + 1] = fmaf(w.y, a0, h3a[4 * q + 1]);
            h3a[4 * q + 2] = fmaf(w.z, a0, h3a[4 * q + 2]);
            h3a[4 * q + 3] = fmaf(w.w, a0, h3a[4 * q + 3]);
            h3b[4 * q + 0] = fmaf(w.x, a1, h3b[4 * q + 0]);
            h3b[4 * q + 1] = fmaf(w.y, a1, h3b[4 * q + 1]);
            h3b[4 * q + 2] = fmaf(w.z, a1, h3b[4 * q + 2]);
            h3b[4 * q + 3] = fmaf(w.w, a1, h3b[4 * q + 3]);
        }
    }

    // ---- layer 4: (1,36) on relu(h3) ----
    float v0 = sb4, v1 = sb4;
#pragma unroll
    for (int q = 0; q < 9; ++q) {
        float4 w = *(const float4*)(&sW4[4 * q]);
        v0 = fmaf(w.x, fmaxf(h3a[4 * q + 0], 0.0f), v0);
        v0 = fmaf(w.y, fmaxf(h3a[4 * q + 1], 0.0f), v0);
        v0 = fmaf(w.z, fmaxf(h3a[4 * q + 2], 0.0f), v0);
        v0 = fmaf(w.w, fmaxf(h3a[4 * q + 3], 0.0f), v0);
        v1 = fmaf(w.x, fmaxf(h3b[4 * q + 0], 0.0f), v1);
        v1 = fmaf(w.y, fmaxf(h3b[4 * q + 1], 0.0f), v1);
        v1 = fmaf(w.z, fmaxf(h3b[4 * q + 2], 0.0f), v1);
        v1 = fmaf(w.w, fmaxf(h3b[4 * q + 3], 0.0f), v1);
    }

    // ---- scatter-max on columns (row index irrelevant after row-max) ----
    int2 p0 = ((const int2*)tidx)[k0];
    int2 p1 = ((const int2*)tidx)[k0 + 1];
    atomicMax(&outU[p0.y], encodeF(v0));
    atomicMax(&outU[p1.y], encodeF(v1));
}

__global__ __launch_bounds__(256) void decode_kernel(unsigned* __restrict__ outU,
                                                     float* __restrict__ outF,
                                                     int out_size) {
    int gid = blockIdx.x * blockDim.x + threadIdx.x;
    if (gid < NCOLS) {
        outF[gid] = decodeF(outU[gid]);
    } else if (gid == NCOLS && out_size > NCOLS) {
        outF[gid] = 1.0f;  // flag
    }
}

extern "C" void kernel_launch(void* const* d_in, const int* in_sizes, int n_in,
                              void* d_out, int out_size, void* d_ws, size_t ws_size,
                              hipStream_t stream) {
    const float* input_1 = (const float*)d_in[0];   // (1,4,1,K)
    const int*   tidx    = (const int*)d_in[1];     // (K,2)
    const float* W1 = (const float*)d_in[2];
    const float* b1 = (const float*)d_in[3];
    const float* W2 = (const float*)d_in[4];
    const float* b2 = (const float*)d_in[5];
    const float* W3 = (const float*)d_in[6];
    const float* b3 = (const float*)d_in[7];
    const float* W4 = (const float*)d_in[8];
    const float* b4 = (const float*)d_in[9];

    unsigned* outU = (unsigned*)d_out;
    float*    outF = (float*)d_out;

    init_kernel<<<(NCOLS + 255) / 256, 256, 0, stream>>>(outU);

    const int nthreads = KN / 2;  // 2 elements per thread
    mlp_scatter_kernel<<<(nthreads + 255) / 256, 256, 0, stream>>>(
        input_1, tidx, W1, b1, W2, b2, W3, b3, W4, b4, outU);

    decode_kernel<<<(out_size + 255) / 256, 256, 0, stream>>>(outU, outF, out_size);
}